// Round 1
// baseline (281.686 us; speedup 1.0000x reference)
//
#include <hip/hip_runtime.h>

// fePAM: per-pixel gather attention.
// B=2, C=64, H=128, W=256, N=H*W=32768, K=32 (fixed by setup_inputs()).
constexpr int B = 2, C = 64, H = 128, W = 256, N = H * W, K = 32;

// ---------------------------------------------------------------------------
// Transpose [B][C][N] -> [B][N][C] for S and R so gathered key/value vectors
// are 256 contiguous bytes. grid = (N/64, B, 2), block = 256.
// ---------------------------------------------------------------------------
__global__ __launch_bounds__(256) void transpose_cn_nc(
    const float* __restrict__ S, const float* __restrict__ R,
    float* __restrict__ St, float* __restrict__ Rt) {
    __shared__ float tile[C][65];  // pad 65: (c+j)%32 -> 2-way (free)
    const int n0 = blockIdx.x * 64;
    const int b  = blockIdx.y;
    const float* src = (blockIdx.z == 0 ? S : R) + (size_t)b * C * N;
    float*       dst = (blockIdx.z == 0 ? St : Rt) + (size_t)b * N * C;

    {
        const int j = threadIdx.x & 63, c0 = threadIdx.x >> 6;
        const float* s = src + n0 + j;
#pragma unroll
        for (int r = 0; r < 16; ++r) {
            int c = c0 + r * 4;
            tile[c][j] = s[(size_t)c * N];          // coalesced along n
        }
    }
    __syncthreads();
    {
        const int c = threadIdx.x & 63, j0 = threadIdx.x >> 6;
#pragma unroll
        for (int r = 0; r < 16; ++r) {
            int j = j0 + r * 4;
            dst[(size_t)(n0 + j) * C + c] = tile[c][j];  // coalesced along c
        }
    }
}

// ---------------------------------------------------------------------------
// Main kernel: one wave per pixel, block = 4 waves = 64-pixel n-tile.
// grid = (N/64, B), block = 256.
// ---------------------------------------------------------------------------
__global__ __launch_bounds__(256) void fepam_attn(
    const float* __restrict__ Q,
    const int*   __restrict__ Px, const int* __restrict__ Py,
    const float* __restrict__ St, const float* __restrict__ Rt,
    float* __restrict__ Out) {
    __shared__ float qt[64][68];   // [n-in-tile][c], pad 68 keeps rows 16B-aligned
    __shared__ float ot[64][65];   // [n-in-tile][c], pad 65 -> 2-way (free)

    const int tid  = threadIdx.x;
    const int lane = tid & 63;
    const int wave = tid >> 6;
    const int b    = blockIdx.y;
    const int n0   = blockIdx.x * 64;

    // ---- stage Q tile: Q[b][c][n0+j] -> qt[j][c] (coalesced global reads)
    {
        const int j = tid & 63, c0 = tid >> 6;
        const float* qsrc = Q + (size_t)b * C * N + n0 + j;
#pragma unroll
        for (int r = 0; r < 16; ++r) {
            int c = c0 + r * 4;
            qt[j][c] = qsrc[(size_t)c * N];
        }
    }
    __syncthreads();

    const int k = lane & 31;      // candidate index this lane owns (phase 1)
    const int h = lane >> 5;      // which half of C this lane covers (phase 1)
    const float* Stb = St + (size_t)b * N * C;
    const float* Rtb = Rt + (size_t)b * N * C;

#pragma unroll 2
    for (int p = 0; p < 16; ++p) {
        const int j = wave * 16 + p;
        const int n = n0 + j;

        // candidate flat index for this lane's k (lanes 32..63 duplicate)
        const int px  = Px[(size_t)n * K + k];
        const int py  = Py[(size_t)n * K + k];
        const int idx = px * W + py;

        // ---- phase 1: score_k = sum_c q[c] * S[idx][c]
        const float4* keyp = (const float4*)(Stb + (size_t)idx * C + h * 32);
        const float4* qp   = (const float4*)(&qt[j][h * 32]);
        float s = 0.f;
#pragma unroll
        for (int i = 0; i < 8; ++i) {
            float4 kv = keyp[i];
            float4 qv = qp[i];
            s += qv.x * kv.x + qv.y * kv.y + qv.z * kv.z + qv.w * kv.w;
        }
        s += __shfl_xor(s, 32);   // combine the two c-halves

        // ---- softmax over the 32 candidates (butterfly in low 5 bits)
        float m = s;
#pragma unroll
        for (int mask = 16; mask >= 1; mask >>= 1)
            m = fmaxf(m, __shfl_xor(m, mask));
        float e = __expf(s - m);
        float l = e;
#pragma unroll
        for (int mask = 16; mask >= 1; mask >>= 1)
            l += __shfl_xor(l, mask);
        const float a = e / l;    // attn weight, valid in lane k (both halves)

        // ---- phase 2: out[c] = sum_k attn_k * R[idx_k][c]; lane = c
        const int c = lane;
        float acc = 0.f;
#pragma unroll
        for (int kk = 0; kk < 32; ++kk) {
            const int   idxk = __builtin_amdgcn_readlane(idx, kk);
            const float ak   = __uint_as_float(
                __builtin_amdgcn_readlane(__float_as_uint(a), kk));
            acc += ak * Rtb[(size_t)idxk * C + c];   // coalesced 256B gather
        }
        ot[j][c] = acc;
    }
    __syncthreads();

    // ---- store: ot[j][c] -> Out[b][c][n0+j] (coalesced along n)
    {
        const int j = tid & 63, c0 = tid >> 6;
        float* od = Out + (size_t)b * C * N + n0 + j;
#pragma unroll
        for (int r = 0; r < 16; ++r) {
            int c = c0 + r * 4;
            od[(size_t)c * N] = ot[j][c];
        }
    }
}

// ---------------------------------------------------------------------------
extern "C" void kernel_launch(void* const* d_in, const int* in_sizes, int n_in,
                              void* d_out, int out_size, void* d_ws, size_t ws_size,
                              hipStream_t stream) {
    const float* Q  = (const float*)d_in[0];
    const float* S  = (const float*)d_in[1];
    const float* R  = (const float*)d_in[2];
    const int*   Px = (const int*)d_in[3];
    const int*   Py = (const int*)d_in[4];
    float* Out = (float*)d_out;

    // workspace: St (16 MB) + Rt (16 MB)
    float* St = (float*)d_ws;
    float* Rt = St + (size_t)B * N * C;

    dim3 tgrid(N / 64, B, 2);
    transpose_cn_nc<<<tgrid, 256, 0, stream>>>(S, R, St, Rt);

    dim3 agrid(N / 64, B);
    fepam_attn<<<agrid, 256, 0, stream>>>(Q, Px, Py, St, Rt, Out);
}

// Round 2
// 149.773 us; speedup vs baseline: 1.8808x; 1.8808x over previous
//
#include <hip/hip_runtime.h>
#include <hip/hip_fp16.h>

// fePAM: per-pixel gather attention.
// B=2, C=64, H=128, W=256, N=H*W=32768, K=32 (fixed by setup_inputs()).
constexpr int B = 2, C = 64, H = 128, W = 256, N = H * W, K = 32;

// ---------------------------------------------------------------------------
// Transpose+downconvert [B][C][N] fp32 -> [B][N][C] fp16 for S and R so each
// gathered key/value vector is 128 contiguous bytes (2 cache lines).
// grid = (N/64, B, 2), block = 256.
// ---------------------------------------------------------------------------
__global__ __launch_bounds__(256) void transpose_cn_nc_h(
    const float* __restrict__ S, const float* __restrict__ R,
    __half* __restrict__ St, __half* __restrict__ Rt) {
    __shared__ float tile[C][65];  // (c*65+j)%32 = (c+j)%32 -> 2-way (free)
    const int n0 = blockIdx.x * 64;
    const int b  = blockIdx.y;
    const float* src = (blockIdx.z == 0 ? S : R) + (size_t)b * C * N;
    __half*      dst = (blockIdx.z == 0 ? St : Rt) + (size_t)b * N * C;

    {   // read: coalesced 256B along n per wave-instruction
        const int j = threadIdx.x & 63, c0 = threadIdx.x >> 6;
        const float* s = src + n0 + j;
#pragma unroll
        for (int r = 0; r < 16; ++r) {
            int c = c0 + r * 4;
            tile[c][j] = s[(size_t)c * N];
        }
    }
    __syncthreads();
    {   // write: half2 per lane, 2 consecutive n-rows per instr = 256B contiguous
        const int c2 = threadIdx.x & 31;       // c-pair
        const int j0 = threadIdx.x >> 5;       // 0..7
        __half2* d2 = (__half2*)dst;
#pragma unroll
        for (int r = 0; r < 8; ++r) {
            int j = j0 + 8 * r;
            d2[(size_t)(n0 + j) * (C / 2) + c2] =
                __floats2half2_rn(tile[2 * c2][j], tile[2 * c2 + 1][j]);
        }
    }
}

// ---------------------------------------------------------------------------
// Main kernel: one wave per pixel, block = 8 waves = 64-pixel n-tile.
// grid = (N/64, B), block = 512. LDS 34KB -> 4 blocks/CU -> 32 waves (100%).
// ---------------------------------------------------------------------------
__global__ __launch_bounds__(512) void fepam_attn(
    const float* __restrict__ Q,
    const int*   __restrict__ Px, const int* __restrict__ Py,
    const __half* __restrict__ St, const __half* __restrict__ Rt,
    float* __restrict__ Out) {
    __shared__ float qt[64][68];   // [n-in-tile][c], rows 16B-aligned (68*4=272)
    __shared__ float ot[64][65];   // [n-in-tile][c], 2-way (free)

    const int tid  = threadIdx.x;
    const int lane = tid & 63;
    const int wave = tid >> 6;     // 0..7
    const int b    = blockIdx.y;
    const int n0   = blockIdx.x * 64;

    // ---- stage Q tile: Q[b][c][n0+j] -> qt[j][c] (coalesced, 8 elems/thread)
    {
        const int j = tid & 63, c0 = tid >> 6;   // c0 in 0..7
        const float* qsrc = Q + (size_t)b * C * N + n0 + j;
#pragma unroll
        for (int r = 0; r < 8; ++r) {
            int c = c0 + r * 8;
            qt[j][c] = qsrc[(size_t)c * N];
        }
    }
    __syncthreads();

    const int k = lane & 31;      // candidate index this lane owns (phase 1)
    const int h = lane >> 5;      // which half of C this lane covers (phase 1)
    const __half* Stb = St + (size_t)b * N * C;
    const __half* Rtb = Rt + (size_t)b * N * C;

#pragma unroll 2
    for (int p = 0; p < 8; ++p) {
        const int j = wave * 8 + p;
        const int n = n0 + j;

        // candidate flat index for this lane's k (lanes 32..63 duplicate)
        const int px  = Px[(size_t)n * K + k];
        const int py  = Py[(size_t)n * K + k];
        const int idx = px * W + py;

        // ---- phase 1: score_k = sum_c q[c] * S[idx][c]   (keys fp16)
        const float4* kp = (const float4*)(Stb + (size_t)idx * C + h * 32); // 64B
        const float4* qp = (const float4*)(&qt[j][h * 32]);
        float s = 0.f;
#pragma unroll
        for (int i = 0; i < 4; ++i) {
            float4 kraw = kp[i];                       // 8 halves
            const __half2* k2 = (const __half2*)&kraw;
            float4 q0 = qp[2 * i], q1 = qp[2 * i + 1];
            float2 f0 = __half22float2(k2[0]);
            float2 f1 = __half22float2(k2[1]);
            float2 f2 = __half22float2(k2[2]);
            float2 f3 = __half22float2(k2[3]);
            s += q0.x * f0.x + q0.y * f0.y + q0.z * f1.x + q0.w * f1.y
               + q1.x * f2.x + q1.y * f2.y + q1.z * f3.x + q1.w * f3.y;
        }
        s += __shfl_xor(s, 32);   // combine the two c-halves

        // ---- softmax over 32 candidates (butterfly in low 5 bits)
        float m = s;
#pragma unroll
        for (int mask = 16; mask >= 1; mask >>= 1)
            m = fmaxf(m, __shfl_xor(m, mask));
        float e = __expf(s - m);
        float l = e;
#pragma unroll
        for (int mask = 16; mask >= 1; mask >>= 1)
            l += __shfl_xor(l, mask);
        const float a = e / l;    // attn weight for candidate k (both halves)

        // ---- phase 2: out[c] = sum_k attn_k * R[idx_k][c]
        // lane = (c-pair, k-parity): each instr gathers TWO 128B value vectors
        const int c2 = lane & 31;
        const int kh = lane >> 5;
        float accx = 0.f, accy = 0.f;
#pragma unroll
        for (int kk = 0; kk < 16; ++kk) {
            const int   srck = 2 * kk + kh;        // lane holding that k
            const int   idxk = __shfl(idx, srck);
            const float ak   = __shfl(a, srck);
            const __half2 v  = *(const __half2*)(Rtb + (size_t)idxk * C + 2 * c2);
            const float2 vf  = __half22float2(v);
            accx += ak * vf.x;
            accy += ak * vf.y;
        }
        accx += __shfl_xor(accx, 32);   // combine even/odd k halves
        accy += __shfl_xor(accy, 32);
        if (lane < 32) {
            ot[j][2 * c2]     = accx;   // stride-2 words: 16 banks x2 = free
            ot[j][2 * c2 + 1] = accy;
        }
    }
    __syncthreads();

    // ---- store: ot[j][c] -> Out[b][c][n0+j] (coalesced along n)
    {
        const int j = tid & 63, c0 = tid >> 6;
        float* od = Out + (size_t)b * C * N + n0 + j;
#pragma unroll
        for (int r = 0; r < 8; ++r) {
            int c = c0 + r * 8;
            od[(size_t)c * N] = ot[j][c];
        }
    }
}

// ---------------------------------------------------------------------------
extern "C" void kernel_launch(void* const* d_in, const int* in_sizes, int n_in,
                              void* d_out, int out_size, void* d_ws, size_t ws_size,
                              hipStream_t stream) {
    const float* Q  = (const float*)d_in[0];
    const float* S  = (const float*)d_in[1];
    const float* R  = (const float*)d_in[2];
    const int*   Px = (const int*)d_in[3];
    const int*   Py = (const int*)d_in[4];
    float* Out = (float*)d_out;

    // workspace: St (4 MB fp16) + Rt (4 MB fp16)
    __half* St = (__half*)d_ws;
    __half* Rt = St + (size_t)B * N * C;

    dim3 tgrid(N / 64, B, 2);
    transpose_cn_nc_h<<<tgrid, 256, 0, stream>>>(S, R, St, Rt);

    dim3 agrid(N / 64, B);
    fepam_attn<<<agrid, 512, 0, stream>>>(Q, Px, Py, St, Rt, Out);
}